// Round 5
// baseline (136.976 us; speedup 1.0000x reference)
//
#include <hip/hip_runtime.h>

// Composite-filter formulation:
//   out[o] = sum_{k=0..54} Cp[r][k] * x[n0 - k],
//     r = (2o+32) % 3, n0 = (2o+32-r)/3,
//     Cp[p][k] = C[p+3k], C[j] = sum_m b[m]*h[j-2m]
// fused_fast covers 50 <= o < n_out; boundary kernel covers o<50 and o>=n_out.
//
// R4 post-mortem: ds_read_b128 with 16B lane stride = structural 8-way bank
// conflict (1.18e7 conflict cycles). R5: interior blocks read the sliding
// window DIRECTLY from global (coalesced dwordx4, 93% L1 reuse); LDS path
// retained only for the 3 edge blocks that need zero-padding guards.

#define TPB 256
#define RPT 6                     // outputs per thread
#define OTILE (TPB * RPT)         // 1536 outputs per block
#define XTILE 1080                // x floats staged per block (edge path)
#define NTAPS 55
#define CPSTRIDE 56               // phase-major coeff stride (zero-padded, float4-aligned)

__global__ void build_coeffs(const float* __restrict__ h,
                             const float* __restrict__ b,
                             float* __restrict__ cp) {
    __shared__ float h_s[63];
    __shared__ float b_s[51];
    const int tid = threadIdx.x;
    if (tid < 63) h_s[tid] = h[tid];
    if (tid < 51) b_s[tid] = b[tid];
    __syncthreads();
    for (int idx = tid; idx < 3 * CPSTRIDE; idx += blockDim.x) {
        const int p = idx / CPSTRIDE;
        const int k = idx - p * CPSTRIDE;
        float acc = 0.0f;
        if (k < NTAPS) {
            const int j = p + 3 * k;
            for (int m = 0; m <= 50; ++m) {
                const int hi = j - 2 * m;
                if (hi >= 0 && hi <= 62) acc += b_s[m] * h_s[hi];
            }
        }
        cp[idx] = acc;
    }
}

// Block 0 = head (o in [0,50)), block 1 = tail (o in [n_out, out_size)).
__global__ __launch_bounds__(128) void boundary_fix(
    const float* __restrict__ x, const float* __restrict__ h,
    const float* __restrict__ b, float* __restrict__ out,
    int n_in, int n_out, int out_size)
{
    __shared__ float h_s[63];
    __shared__ float b_s[51];
    __shared__ float x_s[64];
    __shared__ float u_s[50];

    const int tid = threadIdx.x;
    if (tid < 63) h_s[tid] = h[tid];
    if (tid < 51) b_s[tid] = b[tid];

    if (blockIdx.x == 0) {
        if (tid < 44) x_s[tid] = (tid < n_in) ? x[tid] : 0.0f;
        __syncthreads();
        if (tid < 50) {
            const int s  = 2 * tid + 32;
            const int p0 = s % 3;
            const int q  = s / 3;
            float u = 0.0f;
            #pragma unroll
            for (int i = 0; i <= 20; ++i) {
                const int xi = q - i;
                u += h_s[p0 + 3 * i] * ((xi >= 0) ? x_s[xi] : 0.0f);
            }
            u_s[tid] = u;
        }
        __syncthreads();
        if (tid < 50) {
            float acc = 0.0f;
            for (int t = 0; t <= tid; ++t) acc += b_s[tid - t] * u_s[t];
            out[tid] = acc;
        }
    } else {
        const int t0   = n_out - 50;
        const int qmin = (2 * t0 + 32) / 3;
        const int xb   = qmin - 20;
        if (tid < 64) {
            const int xi = xb + tid;
            x_s[tid] = (xi >= 0 && xi < n_in) ? x[xi] : 0.0f;
        }
        __syncthreads();
        if (tid < 50) {
            const int t  = t0 + tid;
            const int s  = 2 * t + 32;
            const int p0 = s % 3;
            const int q  = s / 3;
            const int base = q - xb;
            float u = 0.0f;
            #pragma unroll
            for (int i = 0; i <= 20; ++i)
                u += h_s[p0 + 3 * i] * x_s[base - i];
            u_s[tid] = u;
        }
        __syncthreads();
        const int n_tail = out_size - n_out;   // 96
        if (tid < n_tail) {
            float acc = 0.0f;
            for (int j = tid; j <= 49; ++j) acc += b_s[tid + 50 - j] * u_s[j];
            out[n_out + tid] = acc;
        }
    }
}

// Core 55-tap x-window convolution over 6 outputs given a float4 stream.
// xs4[j] must yield x[wbase + 4j .. +3] where wbase = n0(ob) - 54.
template <typename F4SRC>
__device__ __forceinline__ void conv6(const F4SRC xs4,
                                      const float4* __restrict__ c2q,
                                      const float4* __restrict__ c1q,
                                      const float4* __restrict__ c0q,
                                      float& a0, float& a1, float& a2,
                                      float& a3, float& a4, float& a5)
{
    float4 hi = xs4[14];
    float4 mi = xs4[13];
#pragma unroll
    for (int g = 0; g < 13; ++g) {
        const float4 lo = xs4[12 - g];
        const float4 q2 = c2q[g];
        const float4 q1 = c1q[g];
        const float4 q0 = c0q[g];
        a0 += q2.x * mi.z;  a1 += q1.x * mi.w;  a2 += q0.x * hi.x;
        a3 += q2.x * hi.x;  a4 += q1.x * hi.y;  a5 += q0.x * hi.z;
        a0 += q2.y * mi.y;  a1 += q1.y * mi.z;  a2 += q0.y * mi.w;
        a3 += q2.y * mi.w;  a4 += q1.y * hi.x;  a5 += q0.y * hi.y;
        a0 += q2.z * mi.x;  a1 += q1.z * mi.y;  a2 += q0.z * mi.z;
        a3 += q2.z * mi.z;  a4 += q1.z * mi.w;  a5 += q0.z * hi.x;
        a0 += q2.w * lo.w;  a1 += q1.w * mi.x;  a2 += q0.w * mi.y;
        a3 += q2.w * mi.y;  a4 += q1.w * mi.z;  a5 += q0.w * mi.w;
        hi = mi; mi = lo;
    }
    {   // tail: k = 52, 53, 54
        const float4 q2 = c2q[13];
        const float4 q1 = c1q[13];
        const float4 q0 = c0q[13];
        a0 += q2.x * mi.z;  a1 += q1.x * mi.w;  a2 += q0.x * hi.x;
        a3 += q2.x * hi.x;  a4 += q1.x * hi.y;  a5 += q0.x * hi.z;
        a0 += q2.y * mi.y;  a1 += q1.y * mi.z;  a2 += q0.y * mi.w;
        a3 += q2.y * mi.w;  a4 += q1.y * hi.x;  a5 += q0.y * hi.y;
        a0 += q2.z * mi.x;  a1 += q1.z * mi.y;  a2 += q0.z * mi.z;
        a3 += q2.z * mi.z;  a4 += q1.z * mi.w;  a5 += q0.z * hi.x;
    }
}

__global__ __launch_bounds__(TPB) void fused_fast(
    const float* __restrict__ x, const float* __restrict__ cp,
    float* __restrict__ out, int n_in, int n_out)
{
    __shared__ float x_s[XTILE];

    const int tid = threadIdx.x;
    const int o0  = blockIdx.x * OTILE;          // multiple of 6
    const int Qb  = (2 * o0 + 30) / 3;           // exact (2*o0 % 3 == 0)
    const int n_tile0 = Qb - 54;                 // lowest x index needed

    const float4* c2q = (const float4*)(cp + 2 * CPSTRIDE);  // phase 2 (o%3==0)
    const float4* c1q = (const float4*)(cp + 1 * CPSTRIDE);
    const float4* c0q = (const float4*)(cp + 0 * CPSTRIDE);

    float a0 = 0.f, a1 = 0.f, a2 = 0.f, a3 = 0.f, a4 = 0.f, a5 = 0.f;

    const bool interior = (n_tile0 >= 0) && (n_tile0 + XTILE <= n_in);
    if (interior) {
        // Direct global reads: lane t, load j -> byte addr 16*(t+j) + base:
        // fully coalesced 1KB per instruction, ~14/15 L1 hit rate.
        const float4* gx4 = (const float4*)(x + n_tile0 + 4 * tid);
        conv6(gx4, c2q, c1q, c0q, a0, a1, a2, a3, a4, a5);
    } else {
        for (int i = tid; i < XTILE; i += TPB) {
            const int n = n_tile0 + i;
            x_s[i] = (n >= 0 && n < n_in) ? x[n] : 0.0f;
        }
        __syncthreads();
        const float4* xs4 = (const float4*)(x_s + 4 * tid);
        conv6(xs4, c2q, c1q, c0q, a0, a1, a2, a3, a4, a5);
    }

    const int ob = o0 + RPT * tid;
    if (ob >= 50 && ob + 5 < n_out) {
        float2* o2 = (float2*)(out + ob);
        o2[0] = make_float2(a0, a1);
        o2[1] = make_float2(a2, a3);
        o2[2] = make_float2(a4, a5);
    } else {
        const float accs[RPT] = {a0, a1, a2, a3, a4, a5};
#pragma unroll
        for (int d = 0; d < RPT; ++d) {
            const int o = ob + d;
            if (o >= 50 && o < n_out) out[o] = accs[d];
        }
    }
}

extern "C" void kernel_launch(void* const* d_in, const int* in_sizes, int n_in_arrs,
                              void* d_out, int out_size, void* d_ws, size_t ws_size,
                              hipStream_t stream) {
    const float* x = (const float*)d_in[0];
    const float* h = (const float*)d_in[1];
    const float* b = (const float*)d_in[2];
    float* out = (float*)d_out;
    float* cp  = (float*)d_ws;                        // 3*56*4 = 672 bytes

    const int n_in  = in_sizes[0];                    // 8388608
    const int n_out = (int)((long long)n_in * 3 / 2); // 12582912

    build_coeffs<<<1, 64, 0, stream>>>(h, b, cp);

    const int nblocks = (n_out + OTILE - 1) / OTILE + 1;
    fused_fast<<<nblocks, TPB, 0, stream>>>(x, cp, out, n_in, n_out);
    boundary_fix<<<2, 128, 0, stream>>>(x, h, b, out, n_in, n_out, out_size);
}

// Round 6
// 121.107 us; speedup vs baseline: 1.1310x; 1.1310x over previous
//
#include <hip/hip_runtime.h>

// Composite-filter formulation:
//   out[o] = sum_{k=0..54} Cp[r][k] * x[n0 - k],
//     r = (2o+32) % 3, n0 = (2o+32-r)/3,
//     Cp[p][k] = C[p+3k], C[j] = sum_m b[m]*h[j-2m]
// fused_fast covers 50 <= o < n_out; boundary kernel covers o<50 and o>=n_out.
//
// R5 post-mortem: VGPR=24 proves the compiler sank the 15 window loads to
// just-before-use -> 13 serial vmcnt round-trips per wave (latency-bound,
// VALUBusy 21%). R6: 15 NAMED float4 loads + sched_barrier(0) fence pins
// them up front; one latency exposure per wave, FMA stream becomes the floor.

#define TPB 256
#define RPT 6                     // outputs per thread
#define OTILE (TPB * RPT)         // 1536 outputs per block
#define XTILE 1080                // x floats staged per block (edge path)
#define NTAPS 55
#define CPSTRIDE 56               // phase-major coeff stride (zero-padded, float4-aligned)

__global__ void build_coeffs(const float* __restrict__ h,
                             const float* __restrict__ b,
                             float* __restrict__ cp) {
    __shared__ float h_s[63];
    __shared__ float b_s[51];
    const int tid = threadIdx.x;
    if (tid < 63) h_s[tid] = h[tid];
    if (tid < 51) b_s[tid] = b[tid];
    __syncthreads();
    for (int idx = tid; idx < 3 * CPSTRIDE; idx += blockDim.x) {
        const int p = idx / CPSTRIDE;
        const int k = idx - p * CPSTRIDE;
        float acc = 0.0f;
        if (k < NTAPS) {
            const int j = p + 3 * k;
            for (int m = 0; m <= 50; ++m) {
                const int hi = j - 2 * m;
                if (hi >= 0 && hi <= 62) acc += b_s[m] * h_s[hi];
            }
        }
        cp[idx] = acc;
    }
}

// Block 0 = head (o in [0,50)), block 1 = tail (o in [n_out, out_size)).
__global__ __launch_bounds__(128) void boundary_fix(
    const float* __restrict__ x, const float* __restrict__ h,
    const float* __restrict__ b, float* __restrict__ out,
    int n_in, int n_out, int out_size)
{
    __shared__ float h_s[63];
    __shared__ float b_s[51];
    __shared__ float x_s[64];
    __shared__ float u_s[50];

    const int tid = threadIdx.x;
    if (tid < 63) h_s[tid] = h[tid];
    if (tid < 51) b_s[tid] = b[tid];

    if (blockIdx.x == 0) {
        if (tid < 44) x_s[tid] = (tid < n_in) ? x[tid] : 0.0f;
        __syncthreads();
        if (tid < 50) {
            const int s  = 2 * tid + 32;
            const int p0 = s % 3;
            const int q  = s / 3;
            float u = 0.0f;
            #pragma unroll
            for (int i = 0; i <= 20; ++i) {
                const int xi = q - i;
                u += h_s[p0 + 3 * i] * ((xi >= 0) ? x_s[xi] : 0.0f);
            }
            u_s[tid] = u;
        }
        __syncthreads();
        if (tid < 50) {
            float acc = 0.0f;
            for (int t = 0; t <= tid; ++t) acc += b_s[tid - t] * u_s[t];
            out[tid] = acc;
        }
    } else {
        const int t0   = n_out - 50;
        const int qmin = (2 * t0 + 32) / 3;
        const int xb   = qmin - 20;
        if (tid < 64) {
            const int xi = xb + tid;
            x_s[tid] = (xi >= 0 && xi < n_in) ? x[xi] : 0.0f;
        }
        __syncthreads();
        if (tid < 50) {
            const int t  = t0 + tid;
            const int s  = 2 * t + 32;
            const int p0 = s % 3;
            const int q  = s / 3;
            const int base = q - xb;
            float u = 0.0f;
            #pragma unroll
            for (int i = 0; i <= 20; ++i)
                u += h_s[p0 + 3 * i] * x_s[base - i];
            u_s[tid] = u;
        }
        __syncthreads();
        const int n_tail = out_size - n_out;   // 96
        if (tid < n_tail) {
            float acc = 0.0f;
            for (int j = tid; j <= 49; ++j) acc += b_s[tid + 50 - j] * u_s[j];
            out[n_out + tid] = acc;
        }
    }
}

// One coefficient group g (taps k=4g..4g+3) against window chunks
// CH = w[14-g], CM = w[13-g], CL = w[12-g].
#define GRP(g, CH, CM, CL) {                                            \
    const float4 q2 = c2q[g];                                           \
    const float4 q1 = c1q[g];                                           \
    const float4 q0 = c0q[g];                                           \
    a0 += q2.x * CM.z;  a1 += q1.x * CM.w;  a2 += q0.x * CH.x;          \
    a3 += q2.x * CH.x;  a4 += q1.x * CH.y;  a5 += q0.x * CH.z;          \
    a0 += q2.y * CM.y;  a1 += q1.y * CM.z;  a2 += q0.y * CM.w;          \
    a3 += q2.y * CM.w;  a4 += q1.y * CH.x;  a5 += q0.y * CH.y;          \
    a0 += q2.z * CM.x;  a1 += q1.z * CM.y;  a2 += q0.z * CM.z;          \
    a3 += q2.z * CM.z;  a4 += q1.z * CM.w;  a5 += q0.z * CH.x;          \
    a0 += q2.w * CL.w;  a1 += q1.w * CM.x;  a2 += q0.w * CM.y;          \
    a3 += q2.w * CM.y;  a4 += q1.w * CM.z;  a5 += q0.w * CM.w; }

#define GRPTAIL(g, CH, CM) {                                            \
    const float4 q2 = c2q[g];                                           \
    const float4 q1 = c1q[g];                                           \
    const float4 q0 = c0q[g];                                           \
    a0 += q2.x * CM.z;  a1 += q1.x * CM.w;  a2 += q0.x * CH.x;          \
    a3 += q2.x * CH.x;  a4 += q1.x * CH.y;  a5 += q0.x * CH.z;          \
    a0 += q2.y * CM.y;  a1 += q1.y * CM.z;  a2 += q0.y * CM.w;          \
    a3 += q2.y * CM.w;  a4 += q1.y * CH.x;  a5 += q0.y * CH.y;          \
    a0 += q2.z * CM.x;  a1 += q1.z * CM.y;  a2 += q0.z * CM.z;          \
    a3 += q2.z * CM.z;  a4 += q1.z * CM.w;  a5 += q0.z * CH.x; }

// Full 55-tap x 6-output convolution: 15 named float4 chunks loaded up front
// (w14 first = first consumed), pinned by sched_barrier, then pure FMA stream.
#define CONV6(SRC) {                                                    \
    const float4 w14 = SRC[14]; const float4 w13 = SRC[13];             \
    const float4 w12 = SRC[12]; const float4 w11 = SRC[11];             \
    const float4 w10 = SRC[10]; const float4 w9  = SRC[9];              \
    const float4 w8  = SRC[8];  const float4 w7  = SRC[7];              \
    const float4 w6  = SRC[6];  const float4 w5  = SRC[5];              \
    const float4 w4  = SRC[4];  const float4 w3  = SRC[3];              \
    const float4 w2  = SRC[2];  const float4 w1  = SRC[1];              \
    const float4 w0  = SRC[0];                                          \
    __builtin_amdgcn_sched_barrier(0);                                  \
    GRP( 0, w14, w13, w12);                                             \
    GRP( 1, w13, w12, w11);                                             \
    GRP( 2, w12, w11, w10);                                             \
    GRP( 3, w11, w10, w9);                                              \
    GRP( 4, w10, w9,  w8);                                              \
    GRP( 5, w9,  w8,  w7);                                              \
    GRP( 6, w8,  w7,  w6);                                              \
    GRP( 7, w7,  w6,  w5);                                              \
    GRP( 8, w6,  w5,  w4);                                              \
    GRP( 9, w5,  w4,  w3);                                              \
    GRP(10, w4,  w3,  w2);                                              \
    GRP(11, w3,  w2,  w1);                                              \
    GRP(12, w2,  w1,  w0);                                              \
    GRPTAIL(13, w1, w0); }

__global__ __launch_bounds__(TPB) void fused_fast(
    const float* __restrict__ x, const float* __restrict__ cp,
    float* __restrict__ out, int n_in, int n_out)
{
    __shared__ float x_s[XTILE];

    const int tid = threadIdx.x;
    const int o0  = blockIdx.x * OTILE;          // multiple of 6
    const int Qb  = (2 * o0 + 30) / 3;           // exact (2*o0 % 3 == 0)
    const int n_tile0 = Qb - 54;                 // lowest x index needed (mult of 4)

    const float4* c2q = (const float4*)(cp + 2 * CPSTRIDE);  // phase 2 (o%3==0)
    const float4* c1q = (const float4*)(cp + 1 * CPSTRIDE);
    const float4* c0q = (const float4*)(cp + 0 * CPSTRIDE);

    float a0 = 0.f, a1 = 0.f, a2 = 0.f, a3 = 0.f, a4 = 0.f, a5 = 0.f;

    const bool interior = (n_tile0 >= 0) && (n_tile0 + XTILE <= n_in);
    if (interior) {
        const float4* gx4 = (const float4*)(x + n_tile0 + 4 * tid);
        CONV6(gx4);
    } else {
        for (int i = tid; i < XTILE; i += TPB) {
            const int n = n_tile0 + i;
            x_s[i] = (n >= 0 && n < n_in) ? x[n] : 0.0f;
        }
        __syncthreads();
        const float4* xs4 = (const float4*)(x_s + 4 * tid);
        CONV6(xs4);
    }

    const int ob = o0 + RPT * tid;
    if (ob >= 50 && ob + 5 < n_out) {
        float2* o2 = (float2*)(out + ob);
        o2[0] = make_float2(a0, a1);
        o2[1] = make_float2(a2, a3);
        o2[2] = make_float2(a4, a5);
    } else {
        const float accs[RPT] = {a0, a1, a2, a3, a4, a5};
#pragma unroll
        for (int d = 0; d < RPT; ++d) {
            const int o = ob + d;
            if (o >= 50 && o < n_out) out[o] = accs[d];
        }
    }
}

extern "C" void kernel_launch(void* const* d_in, const int* in_sizes, int n_in_arrs,
                              void* d_out, int out_size, void* d_ws, size_t ws_size,
                              hipStream_t stream) {
    const float* x = (const float*)d_in[0];
    const float* h = (const float*)d_in[1];
    const float* b = (const float*)d_in[2];
    float* out = (float*)d_out;
    float* cp  = (float*)d_ws;                        // 3*56*4 = 672 bytes

    const int n_in  = in_sizes[0];                    // 8388608
    const int n_out = (int)((long long)n_in * 3 / 2); // 12582912

    build_coeffs<<<1, 64, 0, stream>>>(h, b, cp);

    const int nblocks = (n_out + OTILE - 1) / OTILE + 1;
    fused_fast<<<nblocks, TPB, 0, stream>>>(x, cp, out, n_in, n_out);
    boundary_fix<<<2, 128, 0, stream>>>(x, h, b, out, n_in, n_out, out_size);
}

// Round 7
// 119.497 us; speedup vs baseline: 1.1463x; 1.0135x over previous
//
#include <hip/hip_runtime.h>

// Composite-filter formulation:
//   out[o] = sum_{k=0..54} Cp[r][k] * x[n0 - k],
//     r = (2o+32) % 3, n0 = (2o+32-r)/3,
//     Cp[p][k] = C[p+3k], C[j] = sum_m b[m]*h[j-2m]
// fused_fast covers 50 <= o < n_out; boundary kernel covers o<50 and o>=n_out.
//
// R6 post-mortem: loads pinned, fused ~37us, now L1-BW-bound (40 B L1/output).
// R7: RPT=12 -> 16 window chunks per 12 outputs (21 B/output), VALU becomes
// the floor. Window stays 16B-aligned for every thread (n0 advances by 8
// floats per 12 outputs; wbase = 2048*b - 44 + 8*tid, mult of 4).

#define TPB 256
#define RPT 12                    // outputs per thread
#define OTILE (TPB * RPT)         // 3072 outputs per block
#define XTILE2 2112               // edge-path staging (needs 2104)
#define NTAPS 55
#define CPSTRIDE 56               // phase-major coeff stride (zero-padded, float4-aligned)

__global__ void build_coeffs(const float* __restrict__ h,
                             const float* __restrict__ b,
                             float* __restrict__ cp) {
    __shared__ float h_s[63];
    __shared__ float b_s[51];
    const int tid = threadIdx.x;
    if (tid < 63) h_s[tid] = h[tid];
    if (tid < 51) b_s[tid] = b[tid];
    __syncthreads();
    for (int idx = tid; idx < 3 * CPSTRIDE; idx += blockDim.x) {
        const int p = idx / CPSTRIDE;
        const int k = idx - p * CPSTRIDE;
        float acc = 0.0f;
        if (k < NTAPS) {
            const int j = p + 3 * k;
            for (int m = 0; m <= 50; ++m) {
                const int hi = j - 2 * m;
                if (hi >= 0 && hi <= 62) acc += b_s[m] * h_s[hi];
            }
        }
        cp[idx] = acc;
    }
}

// Block 0 = head (o in [0,50)), block 1 = tail (o in [n_out, out_size)).
__global__ __launch_bounds__(128) void boundary_fix(
    const float* __restrict__ x, const float* __restrict__ h,
    const float* __restrict__ b, float* __restrict__ out,
    int n_in, int n_out, int out_size)
{
    __shared__ float h_s[63];
    __shared__ float b_s[51];
    __shared__ float x_s[64];
    __shared__ float u_s[50];

    const int tid = threadIdx.x;
    if (tid < 63) h_s[tid] = h[tid];
    if (tid < 51) b_s[tid] = b[tid];

    if (blockIdx.x == 0) {
        if (tid < 44) x_s[tid] = (tid < n_in) ? x[tid] : 0.0f;
        __syncthreads();
        if (tid < 50) {
            const int s  = 2 * tid + 32;
            const int p0 = s % 3;
            const int q  = s / 3;
            float u = 0.0f;
            #pragma unroll
            for (int i = 0; i <= 20; ++i) {
                const int xi = q - i;
                u += h_s[p0 + 3 * i] * ((xi >= 0) ? x_s[xi] : 0.0f);
            }
            u_s[tid] = u;
        }
        __syncthreads();
        if (tid < 50) {
            float acc = 0.0f;
            for (int t = 0; t <= tid; ++t) acc += b_s[tid - t] * u_s[t];
            out[tid] = acc;
        }
    } else {
        const int t0   = n_out - 50;
        const int qmin = (2 * t0 + 32) / 3;
        const int xb   = qmin - 20;
        if (tid < 64) {
            const int xi = xb + tid;
            x_s[tid] = (xi >= 0 && xi < n_in) ? x[xi] : 0.0f;
        }
        __syncthreads();
        if (tid < 50) {
            const int t  = t0 + tid;
            const int s  = 2 * t + 32;
            const int p0 = s % 3;
            const int q  = s / 3;
            const int base = q - xb;
            float u = 0.0f;
            #pragma unroll
            for (int i = 0; i <= 20; ++i)
                u += h_s[p0 + 3 * i] * x_s[base - i];
            u_s[tid] = u;
        }
        __syncthreads();
        const int n_tail = out_size - n_out;   // 96
        if (tid < n_tail) {
            float acc = 0.0f;
            for (int j = tid; j <= 49; ++j) acc += b_s[tid + 50 - j] * u_s[j];
            out[n_out + tid] = acc;
        }
    }
}

// Group g covers taps k=4g..4g+3 for 12 outputs d=0..11.
// delta_d = {0,1,2,2,3,4,4,5,6,6,7,8}, phase r_d = (2+2d)%3 -> q2/q1/q0 cycle.
// Window float (54+delta-4g-j) -> chunks: A=w[15-g], B=w[14-g], C=w[13-g], D=w[12-g].
#define GRP12(g, A, B, C, D) {                                          \
    const float4 q2 = c2q[g];                                           \
    const float4 q1 = c1q[g];                                           \
    const float4 q0 = c0q[g];                                           \
    /* j=0 */                                                           \
    a0  += q2.x * C.z;  a1  += q1.x * C.w;  a2  += q0.x * B.x;          \
    a3  += q2.x * B.x;  a4  += q1.x * B.y;  a5  += q0.x * B.z;          \
    a6  += q2.x * B.z;  a7  += q1.x * B.w;  a8  += q0.x * A.x;          \
    a9  += q2.x * A.x;  a10 += q1.x * A.y;  a11 += q0.x * A.z;          \
    /* j=1 */                                                           \
    a0  += q2.y * C.y;  a1  += q1.y * C.z;  a2  += q0.y * C.w;          \
    a3  += q2.y * C.w;  a4  += q1.y * B.x;  a5  += q0.y * B.y;          \
    a6  += q2.y * B.y;  a7  += q1.y * B.z;  a8  += q0.y * B.w;          \
    a9  += q2.y * B.w;  a10 += q1.y * A.x;  a11 += q0.y * A.y;          \
    /* j=2 */                                                           \
    a0  += q2.z * C.x;  a1  += q1.z * C.y;  a2  += q0.z * C.z;          \
    a3  += q2.z * C.z;  a4  += q1.z * C.w;  a5  += q0.z * B.x;          \
    a6  += q2.z * B.x;  a7  += q1.z * B.y;  a8  += q0.z * B.z;          \
    a9  += q2.z * B.z;  a10 += q1.z * B.w;  a11 += q0.z * A.x;          \
    /* j=3 */                                                           \
    a0  += q2.w * D.w;  a1  += q1.w * C.x;  a2  += q0.w * C.y;          \
    a3  += q2.w * C.y;  a4  += q1.w * C.z;  a5  += q0.w * C.w;          \
    a6  += q2.w * C.w;  a7  += q1.w * B.x;  a8  += q0.w * B.y;          \
    a9  += q2.w * B.y;  a10 += q1.w * B.z;  a11 += q0.w * B.w; }

// Tail group: j=0..2 only (k = 52,53,54).
#define GRP12T(g, A, B, C) {                                            \
    const float4 q2 = c2q[g];                                           \
    const float4 q1 = c1q[g];                                           \
    const float4 q0 = c0q[g];                                           \
    a0  += q2.x * C.z;  a1  += q1.x * C.w;  a2  += q0.x * B.x;          \
    a3  += q2.x * B.x;  a4  += q1.x * B.y;  a5  += q0.x * B.z;          \
    a6  += q2.x * B.z;  a7  += q1.x * B.w;  a8  += q0.x * A.x;          \
    a9  += q2.x * A.x;  a10 += q1.x * A.y;  a11 += q0.x * A.z;          \
    a0  += q2.y * C.y;  a1  += q1.y * C.z;  a2  += q0.y * C.w;          \
    a3  += q2.y * C.w;  a4  += q1.y * B.x;  a5  += q0.y * B.y;          \
    a6  += q2.y * B.y;  a7  += q1.y * B.z;  a8  += q0.y * B.w;          \
    a9  += q2.y * B.w;  a10 += q1.y * A.x;  a11 += q0.y * A.y;          \
    a0  += q2.z * C.x;  a1  += q1.z * C.y;  a2  += q0.z * C.z;          \
    a3  += q2.z * C.z;  a4  += q1.z * C.w;  a5  += q0.z * B.x;          \
    a6  += q2.z * B.x;  a7  += q1.z * B.y;  a8  += q0.z * B.z;          \
    a9  += q2.z * B.z;  a10 += q1.z * B.w;  a11 += q0.z * A.x; }

// 55 taps x 12 outputs: 16 named chunks loaded up front (w15 first = first
// consumed), pinned by sched_barrier, then a pure FMA stream.
#define CONV12(SRC) {                                                   \
    const float4 w15 = SRC[15]; const float4 w14 = SRC[14];             \
    const float4 w13 = SRC[13]; const float4 w12 = SRC[12];             \
    const float4 w11 = SRC[11]; const float4 w10 = SRC[10];             \
    const float4 w9  = SRC[9];  const float4 w8  = SRC[8];              \
    const float4 w7  = SRC[7];  const float4 w6  = SRC[6];              \
    const float4 w5  = SRC[5];  const float4 w4  = SRC[4];              \
    const float4 w3  = SRC[3];  const float4 w2  = SRC[2];              \
    const float4 w1  = SRC[1];  const float4 w0  = SRC[0];              \
    __builtin_amdgcn_sched_barrier(0);                                  \
    GRP12( 0, w15, w14, w13, w12);                                      \
    GRP12( 1, w14, w13, w12, w11);                                      \
    GRP12( 2, w13, w12, w11, w10);                                      \
    GRP12( 3, w12, w11, w10, w9);                                       \
    GRP12( 4, w11, w10, w9,  w8);                                       \
    GRP12( 5, w10, w9,  w8,  w7);                                       \
    GRP12( 6, w9,  w8,  w7,  w6);                                       \
    GRP12( 7, w8,  w7,  w6,  w5);                                       \
    GRP12( 8, w7,  w6,  w5,  w4);                                       \
    GRP12( 9, w6,  w5,  w4,  w3);                                       \
    GRP12(10, w5,  w4,  w3,  w2);                                       \
    GRP12(11, w4,  w3,  w2,  w1);                                       \
    GRP12(12, w3,  w2,  w1,  w0);                                       \
    GRP12T(13, w2, w1, w0); }

__global__ __launch_bounds__(TPB) void fused_fast(
    const float* __restrict__ x, const float* __restrict__ cp,
    float* __restrict__ out, int n_in, int n_out)
{
    __shared__ float x_s[XTILE2];

    const int tid = threadIdx.x;
    const int o0  = blockIdx.x * OTILE;          // multiple of 3072
    const int Qb  = (2 * o0 + 30) / 3;           // exact; = 2048*b + 10
    const int n_tile0 = Qb - 54;                 // mult of 4 (2048b - 44)

    const float4* c2q = (const float4*)(cp + 2 * CPSTRIDE);  // phase 2 (o%3==0)
    const float4* c1q = (const float4*)(cp + 1 * CPSTRIDE);
    const float4* c0q = (const float4*)(cp + 0 * CPSTRIDE);

    float a0 = 0.f, a1 = 0.f, a2 = 0.f, a3  = 0.f, a4  = 0.f, a5  = 0.f;
    float a6 = 0.f, a7 = 0.f, a8 = 0.f, a9  = 0.f, a10 = 0.f, a11 = 0.f;

    // Block x-range: [n_tile0, Qb + 2049]; per-thread wbase = n_tile0 + 8*tid.
    const bool interior = (n_tile0 >= 0) && (Qb + 2050 <= n_in);
    if (interior) {
        const float4* gx4 = (const float4*)(x + n_tile0 + 8 * tid);
        CONV12(gx4);
    } else {
        for (int i = tid; i < XTILE2; i += TPB) {
            const int n = n_tile0 + i;
            x_s[i] = (n >= 0 && n < n_in) ? x[n] : 0.0f;
        }
        __syncthreads();
        const float4* xs4 = (const float4*)(x_s) + 2 * tid;
        CONV12(xs4);
    }

    const int ob = o0 + RPT * tid;               // multiple of 12
    if (ob >= 50 && ob + 11 < n_out) {
        float4* o4 = (float4*)(out + ob);        // 16B aligned (ob % 4 == 0)
        o4[0] = make_float4(a0, a1, a2,  a3);
        o4[1] = make_float4(a4, a5, a6,  a7);
        o4[2] = make_float4(a8, a9, a10, a11);
    } else {
        const float accs[RPT] = {a0, a1, a2, a3, a4, a5, a6, a7, a8, a9, a10, a11};
#pragma unroll
        for (int d = 0; d < RPT; ++d) {
            const int o = ob + d;
            if (o >= 50 && o < n_out) out[o] = accs[d];
        }
    }
}

extern "C" void kernel_launch(void* const* d_in, const int* in_sizes, int n_in_arrs,
                              void* d_out, int out_size, void* d_ws, size_t ws_size,
                              hipStream_t stream) {
    const float* x = (const float*)d_in[0];
    const float* h = (const float*)d_in[1];
    const float* b = (const float*)d_in[2];
    float* out = (float*)d_out;
    float* cp  = (float*)d_ws;                        // 3*56*4 = 672 bytes

    const int n_in  = in_sizes[0];                    // 8388608
    const int n_out = (int)((long long)n_in * 3 / 2); // 12582912

    build_coeffs<<<1, 64, 0, stream>>>(h, b, cp);

    const int nblocks = (n_out + OTILE - 1) / OTILE;  // 4096
    fused_fast<<<nblocks, TPB, 0, stream>>>(x, cp, out, n_in, n_out);
    boundary_fix<<<2, 128, 0, stream>>>(x, h, b, out, n_in, n_out, out_size);
}